// Round 2
// baseline (115.653 us; speedup 1.0000x reference)
//
#include <hip/hip_runtime.h>
#include <math.h>

// Problem constants (fixed by setup_inputs)
#define BATCH 8
#define HI 512
#define WI 512
#define HO 256
#define WO 256
#define PLANE (HI*WI)          // 262144 per channel
#define OPIX (HO*WO)           // 65536 output pixels per batch
#define HALF (OPIX/2)          // 32768: rows ih and ih+128 share pix2
// Block: 64 iw-cols x 4 ih-rows x TWO ih-tiles (rows ih, ih+4 of the low half).
// Each thread owns a vertical QUAD: pixels (ih,iw),(ih+128,iw),(ih+4,iw),(ih+132,iw).
// Tile-1's global loads are issued before the barrier and drain under tile-0's
// compute (in-order vmcnt); raw s_barrier + manual lgkmcnt(0) avoids the
// compiler's full vmcnt(0) drain that would kill the prefetch.
#define LROWS 68
#define LCOLS 10
#define LQ 11                  // float4 per row: 10 data + 1 pad

__device__ __forceinline__ int lds_off(float ox, float oy, float kxf, float kyf,
                                       float uu_own, int w0)
{
    // reference fp32 op order preserved
    const float cx = ((ox + 1.5f) + kxf) + uu_own;
    const float cy = ((oy + 1.5f) + kyf) + uu_own;
    const int x0 = (int)floorf(cx);        // row in [iw+2, iw+5]
    const int y0 = (int)floorf(cy);        // col in [iw+2, iw+5]
    return (((x0 - 2 - w0) * LQ) + (y0 - x0 + 3)) << 4;   // byte offset of q[0]
}

__device__ __forceinline__ void compute_tile(
    const char* sbase, const int* offA, const int* offB,
    const float2* sx, const float2* sy, const float* kvA, const float* kvB,
    float uu_s0, float uu_s1,
    float* aA, float* aB)
{
    #pragma unroll
    for (int k = 0; k < 9; ++k) {
        // ---- scrambled weights: computed ONCE, identical for both pixels ----
        const int ta = 2 * k, tb = 2 * k + 1;
        const int sel_a = (ta >= 9) ? 1 : 0;
        const int sel_b = (tb >= 9) ? 1 : 0;
        const int ks_a = ta - 9 * sel_a;           // compile-time after unroll
        const int ks_b = tb - 9 * sel_b;
        const float uu_a = sel_a ? uu_s1 : uu_s0;
        const float uu_b = sel_b ? uu_s1 : uu_s0;
        const float oxa  = sel_a ? sx[ks_a].y : sx[ks_a].x;
        const float oya  = sel_a ? sy[ks_a].y : sy[ks_a].x;
        const float oxb2 = sel_b ? sx[ks_b].y : sx[ks_b].x;
        const float oyb2 = sel_b ? sy[ks_b].y : sy[ks_b].x;
        const float kxa = (float)(ks_a / 3), kya = (float)(ks_a - 3 * (ks_a / 3));
        const float kxb = (float)(ks_b / 3), kyb = (float)(ks_b - 3 * (ks_b / 3));

        const float cxa = ((oxa + 1.5f) + kxa) + uu_a;    // reference fp32 op order
        const float cya = ((oya + 1.5f) + kya) + uu_a;
        const float cxb = ((oxb2 + 1.5f) + kxb) + uu_b;
        const float cyb = ((oyb2 + 1.5f) + kyb) + uu_b;
        const float fxa = cxa - floorf(cxa);   // exact (Sterbenz)
        const float fya = cya - floorf(cya);
        const float fxb = cxb - floorf(cxb);
        const float fyb = cyb - floorf(cyb);

        // pixel A (ih<128): flip -> (1-f); pixel B: f.  Static per half.
        const float w0A = 1.0f - fxa, w1A = 1.0f - fxb;
        const float v0A = 1.0f - fya, v1A = 1.0f - fyb;
        const float A00 = w0A * v0A, A10 = w1A * v0A, A01 = w0A * v1A, A11 = w1A * v1A;
        const float B00 = fxa * fya, B10 = fxb * fya, B01 = fxa * fyb, B11 = fxb * fyb;

        {   // pixel A corners + bilinear (scrambled channel/corner table)
            const float4* q = (const float4*)(sbase + offA[k]);
            const float4 Ia = q[1];
            const float4 Ib = q[2];
            const float4 Ic = q[LQ];
            const float4 Id = q[LQ + 1];
            const float p0 = A00 * Ib.x + A10 * Ic.x + A01 * Id.y + A11 * Ia.z;
            const float p1 = A00 * Ia.x + A10 * Ib.y + A01 * Ic.y + A11 * Id.z;
            const float p2 = A00 * Id.x + A10 * Ia.y + A01 * Ib.z + A11 * Ic.z;
            aA[0] += kvA[k] * p0;
            aA[1] += kvA[k] * p1;
            aA[2] += kvA[k] * p2;
        }
        {   // pixel B corners + bilinear
            const float4* q = (const float4*)(sbase + offB[k]);
            const float4 Ia = q[1];
            const float4 Ib = q[2];
            const float4 Ic = q[LQ];
            const float4 Id = q[LQ + 1];
            const float p0 = B00 * Ib.x + B10 * Ic.x + B01 * Id.y + B11 * Ia.z;
            const float p1 = B00 * Ia.x + B10 * Ib.y + B01 * Ic.y + B11 * Id.z;
            const float p2 = B00 * Id.x + B10 * Ia.y + B01 * Ib.z + B11 * Ic.z;
            aB[0] += kvB[k] * p0;
            aB[1] += kvB[k] * p1;
            aB[2] += kvB[k] * p2;
        }
    }
}

__device__ __forceinline__ void store3(float* __restrict__ out, size_t obase,
                                       float a0, float a1, float a2)
{
    // softround(out * 255) via HW sin (input in revolutions)
    const float TWO_PI_INV = 0.15915494309189533577f;
    const float z0 = a0 * 255.0f;
    const float z1 = a1 * 255.0f;
    const float z2 = a2 * 255.0f;
    const float r0s = z0 - rintf(z0);   // exact; sin(2*pi*z) = sin(2*pi*r)
    const float r1s = z1 - rintf(z1);
    const float r2s = z2 - rintf(z2);
    out[obase + 0] = z0 - __builtin_amdgcn_sinf(r0s) * TWO_PI_INV;
    out[obase + 1] = z1 - __builtin_amdgcn_sinf(r1s) * TWO_PI_INV;
    out[obase + 2] = z2 - __builtin_amdgcn_sinf(r2s) * TWO_PI_INV;
}

__global__ __launch_bounds__(256, 2) void downsampler_kernel(
    const float* __restrict__ images,
    const float* __restrict__ kernels,
    const float* __restrict__ offx,
    const float* __restrict__ offy,
    float* __restrict__ out)
{
    __shared__ float4 simg[LROWS * LQ];   // 11968 B, shared by BOTH tiles

    const int blk  = blockIdx.x;          // 512 blocks
    const int b    = blk >> 6;            // batch
    const int ihx  = (blk >> 2) & 15;     // ih-tile-pair (8 rows of the low half)
    const int w0   = (blk & 3) << 6;      // iw-tile base (64 cols)
    const int tid  = threadIdx.x;
    const int lane = tid & 63;
    const int iw   = w0 + lane;
    const int ihA0 = (ihx << 3) + (tid >> 6);   // tile0 row, in [0,124]
    const int plA0 = ihA0 * WO + iw;            // < HALF, so pix2 == plA0
    const int plA1 = plA0 + 4 * WO;             // tile1: row ihA0+4  (<= 127)

    const float* offxb = offx    + (size_t)b * 9 * OPIX;
    const float* offyb = offy    + (size_t)b * 9 * OPIX;
    const float* kernb = kernels + (size_t)b * 9 * OPIX;

    // ==== TILE 0 loads (72): own coords, shared scrambled pairs, kernel wts ====
    float oxA0[9], oyA0[9], oxB0[9], oyB0[9];
    float2 sx0[9], sy0[9];
    float  kvA0[9], kvB0[9];
    #pragma unroll
    for (int k = 0; k < 9; ++k) {
        oxA0[k] = offxb[k * OPIX + plA0];
        oyA0[k] = offyb[k * OPIX + plA0];
        oxB0[k] = offxb[k * OPIX + plA0 + HALF];
        oyB0[k] = offyb[k * OPIX + plA0 + HALF];
        sx0[k]  = ((const float2*)(offxb + k * OPIX))[plA0];
        sy0[k]  = ((const float2*)(offyb + k * OPIX))[plA0];
        kvA0[k] = kernb[k * OPIX + plA0];
        kvB0[k] = kernb[k * OPIX + plA0 + HALF];
    }

    // ---- image band staging: depends on (b,w0) only -> serves BOTH tiles ----
    // I(r, c, .) = simg[(r-(w0+2))*11 + (c-(r-4))], r in [w0+2, w0+70)
    {
        const float* imb = images + (size_t)b * 3 * PLANE;
        #pragma unroll
        for (int ii = 0; ii < 3; ++ii) {
            const int i = tid + ii * 256;
            if (i < LROWS * LCOLS) {
                const int row = i / LCOLS;
                const int col = i - row * LCOLS;
                const int r = w0 + 2 + row;
                int c = r - 4 + col;
                c = c < 0 ? 0 : c;   // upper clamp provably inactive (c <= 266)
                const float* src = imb + r * WI + c;
                simg[row * LQ + col] =
                    make_float4(src[0], src[PLANE], src[2 * PLANE], 0.0f);
            }
        }
    }

    // ==== TILE 1 loads (72): issued BEFORE the barrier, drain under T0 compute ====
    float oxA1[9], oyA1[9], oxB1[9], oyB1[9];
    float2 sx1[9], sy1[9];
    float  kvA1[9], kvB1[9];
    #pragma unroll
    for (int k = 0; k < 9; ++k) {
        oxA1[k] = offxb[k * OPIX + plA1];
        oyA1[k] = offyb[k * OPIX + plA1];
        oxB1[k] = offxb[k * OPIX + plA1 + HALF];
        oyB1[k] = offyb[k * OPIX + plA1 + HALF];
        sx1[k]  = ((const float2*)(offxb + k * OPIX))[plA1];
        sy1[k]  = ((const float2*)(offyb + k * OPIX))[plA1];
        kvA1[k] = kernb[k * OPIX + plA1];
        kvB1[k] = kernb[k * OPIX + plA1 + HALF];
    }

    // ==== TILE 0 address prep (own coords -> LDS byte offsets, frees 36 VGPRs) ====
    const float uu_own = (float)iw + 0.5f;
    int offA0_[9], offB0_[9];
    #pragma unroll
    for (int k = 0; k < 9; ++k) {
        const float kxf = (float)(k / 3);
        const float kyf = (float)(k - 3 * (k / 3));
        offA0_[k] = lds_off(oxA0[k], oyA0[k], kxf, kyf, uu_own, w0);
        offB0_[k] = lds_off(oxB0[k], oyB0[k], kxf, kyf, uu_own, w0);
    }

    // ---- barrier WITHOUT vmcnt(0) drain: only LDS writes must be visible ----
    __builtin_amdgcn_sched_barrier(0);               // pin loads + addr prep above
    asm volatile("s_waitcnt lgkmcnt(0)" ::: "memory");
    __builtin_amdgcn_s_barrier();
    __builtin_amdgcn_sched_barrier(0);               // pin LDS reads below

    const float uu_s0 = (float)((2 * iw) & 255) + 0.5f;
    const float uu_s1 = uu_s0 + 1.0f;
    const char* sbase = (const char*)simg;

    // ==== TILE 0 compute + store (tile-1 loads drain underneath) ====
    {
        float aA[3] = {0.f, 0.f, 0.f}, aB[3] = {0.f, 0.f, 0.f};
        compute_tile(sbase, offA0_, offB0_, sx0, sy0, kvA0, kvB0,
                     uu_s0, uu_s1, aA, aB);
        store3(out, ((size_t)b * OPIX + (size_t)plA0) * 3, aA[0], aA[1], aA[2]);
        store3(out, ((size_t)b * OPIX + (size_t)(plA0 + HALF)) * 3, aB[0], aB[1], aB[2]);
    }

    // ==== TILE 1 address prep (waits only on tile-1 own loads) + compute ====
    {
        int offA1_[9], offB1_[9];
        #pragma unroll
        for (int k = 0; k < 9; ++k) {
            const float kxf = (float)(k / 3);
            const float kyf = (float)(k - 3 * (k / 3));
            offA1_[k] = lds_off(oxA1[k], oyA1[k], kxf, kyf, uu_own, w0);
            offB1_[k] = lds_off(oxB1[k], oyB1[k], kxf, kyf, uu_own, w0);
        }
        float aA[3] = {0.f, 0.f, 0.f}, aB[3] = {0.f, 0.f, 0.f};
        compute_tile(sbase, offA1_, offB1_, sx1, sy1, kvA1, kvB1,
                     uu_s0, uu_s1, aA, aB);
        store3(out, ((size_t)b * OPIX + (size_t)plA1) * 3, aA[0], aA[1], aA[2]);
        store3(out, ((size_t)b * OPIX + (size_t)(plA1 + HALF)) * 3, aB[0], aB[1], aB[2]);
    }
}

extern "C" void kernel_launch(void* const* d_in, const int* in_sizes, int n_in,
                              void* d_out, int out_size, void* d_ws, size_t ws_size,
                              hipStream_t stream) {
    const float* images  = (const float*)d_in[0];
    const float* kernels = (const float*)d_in[1];
    const float* offx    = (const float*)d_in[2];
    const float* offy    = (const float*)d_in[3];
    float* out = (float*)d_out;

    dim3 grid(BATCH * 16 * 4);   // 512 blocks: (b, 8-row ih-tile-pair, iw-tile)
    dim3 block(256);             // 64 iw-lanes x 4 waves, one vertical QUAD/thread
    hipLaunchKernelGGL(downsampler_kernel, grid, block, 0, stream,
                       images, kernels, offx, offy, out);
}

// Round 7
// 113.537 us; speedup vs baseline: 1.0186x; 1.0186x over previous
//
#include <hip/hip_runtime.h>
#include <math.h>

// Problem constants (fixed by setup_inputs)
#define BATCH 8
#define HI 512
#define WI 512
#define HO 256
#define WO 256
#define PLANE (HI*WI)          // 262144 per channel
#define OPIX (HO*WO)           // 65536 output pixels per batch
// Block tile: 64 iw-cols x 4 ih-rows, 1 pixel per thread.
// Gather footprint for iw in [w0,w0+64): image rows/cols in [w0+2, w0+70).
#define LROWS 68
#define LCOLS 10
#define LQ 11                  // float4 per row: 10 data + 1 pad (176 B, 16B-aligned)

__global__ __launch_bounds__(256) void downsampler_kernel(
    const float* __restrict__ images,
    const float* __restrict__ kernels,
    const float* __restrict__ offx,
    const float* __restrict__ offy,
    float* __restrict__ out)
{
    __shared__ float4 simg[LROWS * LQ];   // 11968 B

    const int blk  = blockIdx.x;          // 2048 blocks
    const int b    = blk >> 8;            // batch
    const int ihx  = (blk >> 2) & 63;     // ih-tile (4 rows)
    const int w0   = (blk & 3) << 6;      // iw-tile base (64 cols)
    const int tid  = threadIdx.x;
    const int lane = tid & 63;
    const int iw   = w0 + lane;
    const int ih   = (ihx << 2) + (tid >> 6);   // wave-uniform

    const float* offxb = offx    + (size_t)b * 9 * OPIX;
    const float* offyb = offy    + (size_t)b * 9 * OPIX;
    const float* kernb = kernels + (size_t)b * 9 * OPIX;

    const int pl   = ih * WO + iw;
    const int pix2 = pl & (OPIX / 2 - 1);  // float2 index of scrambled pair (2pl, 2pl+1)

    // ==== PHASE 1: issue ALL compulsory global loads back-to-back (max MLP) ====
    // 27 dword + 18 dwordx2 = 45 loads, ~16 KB per wave in flight.
    float  ox_[9], oy_[9], kv_[9];
    float2 sx_[9], sy_[9];
    #pragma unroll
    for (int k = 0; k < 9; ++k) {
        ox_[k] = offxb[k * OPIX + pl];
        oy_[k] = offyb[k * OPIX + pl];
        kv_[k] = kernb[k * OPIX + pl];
        sx_[k] = ((const float2*)(offxb + k * OPIX))[pix2];
        sy_[k] = ((const float2*)(offyb + k * OPIX))[pix2];
    }

    // ---- image band staging (issued after the batch; single FIFO drain) ----
    // I(r, c, .) = simg[(r-(w0+2))*11 + (c-(r-4))], r in [w0+2, w0+70)
    {
        const float* imb = images + (size_t)b * 3 * PLANE;
        #pragma unroll
        for (int ii = 0; ii < 3; ++ii) {
            const int i = tid + ii * 256;
            if (i < LROWS * LCOLS) {
                const int row = i / LCOLS;
                const int col = i - row * LCOLS;
                const int r = w0 + 2 + row;
                int c = r - 4 + col;
                c = c < 0 ? 0 : c;   // upper clamp provably inactive (c <= 266)
                const float* src = imb + r * WI + c;
                simg[row * LQ + col] =
                    make_float4(src[0], src[PLANE], src[2 * PLANE], 0.0f);
            }
        }
    }
    __builtin_amdgcn_sched_barrier(0);   // pin the load batch above all uses
    __syncthreads();

    // ==== PHASE 2: pure compute from registers + LDS ====
    const bool flip = (ih < 128);          // wave-uniform
    const float uu_own = (float)iw + 0.5f;
    const float uu_s0  = (float)((2 * iw) & 255) + 0.5f;
    const float uu_s1  = uu_s0 + 1.0f;     // no wrap: (2iw)&255 is even <= 254

    float acc0 = 0.f, acc1 = 0.f, acc2 = 0.f;

    #pragma unroll
    for (int k = 0; k < 9; ++k) {
        // ---- own coords -> gather corners from LDS ----
        const float kxf = (float)(k / 3);
        const float kyf = (float)(k - 3 * (k / 3));
        const float cx = ((ox_[k] + 1.5f) + kxf) + uu_own;   // reference fp32 op order
        const float cy = ((oy_[k] + 1.5f) + kyf) + uu_own;
        const int x0 = (int)floorf(cx);        // row in [iw+2, iw+5]
        const int y0 = (int)floorf(cy);        // col in [iw+2, iw+5]
        const int rowrel = x0 - 2 - w0;        // [lane, lane+3]
        const int colq   = y0 - x0 + 4;        // [1, 7]
        const float4* qa = &simg[rowrel * LQ + (colq - 1)];
        const float4 Ia = qa[1];               // (x0,y0)
        const float4 Ib = qa[2];               // (x0,y1)
        const float4 Ic = qa[LQ];              // (x1,y0)
        const float4 Id = qa[LQ + 1];          // (x1,y1)

        // ---- scrambled weights for taps t=2k, 2k+1 ----
        const int ta = 2 * k, tb = 2 * k + 1;
        const int sel_a = (ta >= 9) ? 1 : 0;
        const int sel_b = (tb >= 9) ? 1 : 0;
        const int ks_a = ta - 9 * sel_a;
        const int ks_b = tb - 9 * sel_b;
        const float uu_a = sel_a ? uu_s1 : uu_s0;
        const float uu_b = sel_b ? uu_s1 : uu_s0;
        const float oxa  = sel_a ? sx_[ks_a].y : sx_[ks_a].x;
        const float oya  = sel_a ? sy_[ks_a].y : sy_[ks_a].x;
        const float oxb2 = sel_b ? sx_[ks_b].y : sx_[ks_b].x;
        const float oyb2 = sel_b ? sy_[ks_b].y : sy_[ks_b].x;
        const float kxa = (float)(ks_a / 3), kya = (float)(ks_a - 3 * (ks_a / 3));
        const float kxb = (float)(ks_b / 3), kyb = (float)(ks_b - 3 * (ks_b / 3));

        const float cxa = ((oxa + 1.5f) + kxa) + uu_a;    // reference fp32 op order
        const float cya = ((oya + 1.5f) + kya) + uu_a;
        const float cxb = ((oxb2 + 1.5f) + kxb) + uu_b;
        const float cyb = ((oyb2 + 1.5f) + kyb) + uu_b;
        const float fxa = cxa - floorf(cxa);   // exact (Sterbenz)
        const float fya = cya - floorf(cya);
        const float fxb = cxb - floorf(cxb);
        const float fyb = cyb - floorf(cyb);
        const float w0w = flip ? (1.0f - fxa) : fxa;   // wx[2k]
        const float w1w = flip ? (1.0f - fxb) : fxb;   // wx[2k+1]
        const float v0w = flip ? (1.0f - fya) : fya;   // wy[2k]
        const float v1w = flip ? (1.0f - fyb) : fyb;   // wy[2k+1]

        const float w0v0 = w0w * v0w, w1v0 = w1w * v0w;
        const float w0v1 = w0w * v1w, w1v1 = w1w * v1w;

        // scrambled channel/corner table
        const float p0 = w0v0 * Ib.x + w1v0 * Ic.x + w0v1 * Id.y + w1v1 * Ia.z;
        const float p1 = w0v0 * Ia.x + w1v0 * Ib.y + w0v1 * Ic.y + w1v1 * Id.z;
        const float p2 = w0v0 * Id.x + w1v0 * Ia.y + w0v1 * Ib.z + w1v1 * Ic.z;

        acc0 += kv_[k] * p0;
        acc1 += kv_[k] * p1;
        acc2 += kv_[k] * p2;
    }

    // ---- softround(out * 255) via HW sin (input in revolutions) ----
    const float TWO_PI_INV = 0.15915494309189533577f;
    const size_t obase = ((size_t)b * OPIX + (size_t)pl) * 3;
    const float z0 = acc0 * 255.0f;
    const float z1 = acc1 * 255.0f;
    const float z2 = acc2 * 255.0f;
    const float r0s = z0 - rintf(z0);   // exact; sin(2*pi*z) = sin(2*pi*r)
    const float r1s = z1 - rintf(z1);
    const float r2s = z2 - rintf(z2);
    out[obase + 0] = z0 - __builtin_amdgcn_sinf(r0s) * TWO_PI_INV;
    out[obase + 1] = z1 - __builtin_amdgcn_sinf(r1s) * TWO_PI_INV;
    out[obase + 2] = z2 - __builtin_amdgcn_sinf(r2s) * TWO_PI_INV;
}

extern "C" void kernel_launch(void* const* d_in, const int* in_sizes, int n_in,
                              void* d_out, int out_size, void* d_ws, size_t ws_size,
                              hipStream_t stream) {
    const float* images  = (const float*)d_in[0];
    const float* kernels = (const float*)d_in[1];
    const float* offx    = (const float*)d_in[2];
    const float* offy    = (const float*)d_in[3];
    float* out = (float*)d_out;

    dim3 grid(BATCH * 64 * 4);   // 2048 blocks: (b, ih-tile of 4, iw-tile of 64)
    dim3 block(256);             // 64 iw-lanes x 4 waves, 1 pixel per thread
    hipLaunchKernelGGL(downsampler_kernel, grid, block, 0, stream,
                       images, kernels, offx, offy, out);
}